// Round 17
// baseline (165.238 us; speedup 1.0000x reference)
//
#include <hip/hip_runtime.h>
#include <hip/hip_bf16.h>
#include <math.h>

#define NN 4096
#define DIN 1024
#define NH 16
#define DH 64

typedef unsigned short u16;
typedef unsigned long long u64;
typedef u16 u16x4 __attribute__((ext_vector_type(4)));
typedef u16 u16x8 __attribute__((ext_vector_type(8)));
typedef unsigned ux2 __attribute__((ext_vector_type(2)));
typedef unsigned ux4 __attribute__((ext_vector_type(4)));
typedef float fx4 __attribute__((ext_vector_type(4)));
typedef __bf16 bf16x8 __attribute__((ext_vector_type(8)));
typedef _Float16 h16x8 __attribute__((ext_vector_type(8)));

__device__ __forceinline__ u16 f2b(float f) {
  unsigned u = __float_as_uint(f);
  u += 0x7fff + ((u >> 16) & 1);
  return (u16)(u >> 16);
}
__device__ __forceinline__ float b2f(u16 h) {
  return __uint_as_float(((unsigned)h) << 16);
}
__device__ __forceinline__ u16 f2h_bits(float f) {
  _Float16 h = (_Float16)f;
  return __builtin_bit_cast(unsigned short, h);
}
__device__ __forceinline__ unsigned pack2h(float f) {
  unsigned hb = (unsigned)f2h_bits(f);
  return hb | (hb << 16);
}
__device__ __forceinline__ unsigned pk_mul(unsigned a, unsigned b) {
  unsigned d;
  asm("v_pk_mul_f16 %0, %1, %2" : "=v"(d) : "v"(a), "v"(b));
  return d;
}
__device__ __forceinline__ unsigned pk_max(unsigned a, unsigned b) {
  unsigned d;
  asm("v_pk_max_f16 %0, %1, %2" : "=v"(d) : "v"(a), "v"(b));
  return d;
}
// async global->LDS, 16B per lane; lds base wave-uniform, lane*16 auto-offset
__device__ __forceinline__ void gload16(const void* g, void* l) {
  __builtin_amdgcn_global_load_lds(
      (const __attribute__((address_space(1))) unsigned*)g,
      (__attribute__((address_space(3))) unsigned*)l, 16, 0, 0);
}
__device__ __forceinline__ void wait_vm6() {
  asm volatile("s_waitcnt vmcnt(6)" ::: "memory");
}
__device__ __forceinline__ void wait_vm8() {
  asm volatile("s_waitcnt vmcnt(8)" ::: "memory");
}

// ---------------- cast f32 -> bf16 (flat) ----------------
__global__ __launch_bounds__(256) void cast_kernel(const float* __restrict__ in,
                                                   u16* __restrict__ out, int n4) {
  int i = blockIdx.x * 256 + threadIdx.x;
  if (i < n4) {
    fx4 v = reinterpret_cast<const fx4*>(in)[i];
    u16x4 o;
    o[0] = f2b(v[0]); o[1] = f2b(v[1]); o[2] = f2b(v[2]); o[3] = f2b(v[3]);
    reinterpret_cast<u16x4*>(out)[i] = o;
  }
}

// ---------------- transpose+cast f32[R][C] -> bf16[C][R] ----------------
__global__ __launch_bounds__(256) void tcast_kernel(const float* __restrict__ in,
                                                    u16* __restrict__ out, int R, int C) {
  __shared__ u16 tile[32][33];
  int bc = blockIdx.x * 32, br = blockIdx.y * 32;
  int tx = threadIdx.x & 31, ty = threadIdx.x >> 5;
  #pragma unroll
  for (int r = ty; r < 32; r += 8)
    tile[r][tx] = f2b(in[(size_t)(br + r) * C + bc + tx]);
  __syncthreads();
  #pragma unroll
  for (int r = ty; r < 32; r += 8)
    out[(size_t)(bc + r) * R + br + tx] = tile[tx][r];
}

// ---- gemm1 fused: seq = xb@W_seq^T; writes seqTh (f16, [d][n]) + score partials ----
__global__ __launch_bounds__(256, 2) void gemm_seq(const u16* __restrict__ A,
                                                   const u16* __restrict__ BT,
                                                   const float* __restrict__ a1,
                                                   const float* __restrict__ a2,
                                                   u16* __restrict__ seqTh,
                                                   float* __restrict__ s1T,
                                                   float* __restrict__ s2H,
                                                   int K) {
  __shared__ __align__(16) u16 As[2][128 * 64];   // 2 x 16 KB
  __shared__ __align__(16) u16 Bs[2][64 * 64];    // 2 x 8 KB
  const int tid = threadIdx.x;
  const int i0 = blockIdx.x * 128, n0 = blockIdx.y * 64, h = blockIdx.y;
  const int w = tid >> 6, l = tid & 63;
  const int wr = w >> 1, wc = w & 1;
  const int lr = l & 15, lslot = l >> 4;
  const int wu = __builtin_amdgcn_readfirstlane(w);
  const int srow_lo = l >> 3, sg = (l & 7) ^ (srow_lo & 7);
  const u16* gA[4];
  #pragma unroll
  for (int jj = 0; jj < 4; jj++)
    gA[jj] = A + (size_t)(i0 + wu * 32 + jj * 8 + srow_lo) * K + sg * 8;
  const u16* gB[2];
  #pragma unroll
  for (int jb = 0; jb < 2; jb++)
    gB[jb] = BT + (size_t)(n0 + wu * 16 + jb * 8 + srow_lo) * K + sg * 8;

  fx4 acc[4][2] = {};

  #pragma unroll
  for (int jj = 0; jj < 4; jj++)
    gload16(gA[jj], (char*)As[0] + wu * 4096 + jj * 1024);
  #pragma unroll
  for (int jb = 0; jb < 2; jb++)
    gload16(gB[jb], (char*)Bs[0] + wu * 2048 + jb * 1024);
  __syncthreads();

  for (int kt = 0; kt < 16; kt++) {
    const int buf = kt & 1;
    __builtin_amdgcn_s_barrier();
    {
      const int kn = ((kt + 1) & 15) * 64;
      __builtin_amdgcn_sched_barrier(0);
      #pragma unroll
      for (int jj = 0; jj < 4; jj++)
        gload16(gA[jj] + kn, (char*)As[buf ^ 1] + wu * 4096 + jj * 1024);
      #pragma unroll
      for (int jb = 0; jb < 2; jb++)
        gload16(gB[jb] + kn, (char*)Bs[buf ^ 1] + wu * 2048 + jb * 1024);
      __builtin_amdgcn_sched_barrier(0);
      wait_vm6();
      __builtin_amdgcn_sched_barrier(0);
    }
    __builtin_amdgcn_s_barrier();
    #pragma unroll
    for (int ks = 0; ks < 2; ks++) {
      bf16x8 af[4], bfr[2];
      #pragma unroll
      for (int mi = 0; mi < 4; mi++) {
        const int r = wr * 64 + mi * 16 + lr;
        const int sl = (ks * 4 + lslot) ^ (r & 7);
        af[mi] = *reinterpret_cast<const bf16x8*>((const char*)As[buf] + r * 128 + sl * 16);
      }
      #pragma unroll
      for (int ni = 0; ni < 2; ni++) {
        const int r = wc * 32 + ni * 16 + lr;
        const int sl = (ks * 4 + lslot) ^ (r & 7);
        bfr[ni] = *reinterpret_cast<const bf16x8*>((const char*)Bs[buf] + r * 128 + sl * 16);
      }
      #pragma unroll
      for (int mi = 0; mi < 4; mi++)
        #pragma unroll
        for (int ni = 0; ni < 2; ni++)
          acc[mi][ni] = __builtin_amdgcn_mfma_f32_16x16x32_bf16(af[mi], bfr[ni], acc[mi][ni], 0, 0, 0);
    }
  }
  __syncthreads();   // all compute done before As is reused as transpose scratch

  // ---- score partials ----
  float a1v[2], a2v[2];
  #pragma unroll
  for (int ni = 0; ni < 2; ni++) {
    int dl = wc * 32 + ni * 16 + lr;
    a1v[ni] = a1[dl];
    a2v[ni] = a2[dl];
  }
  #pragma unroll
  for (int mi = 0; mi < 4; mi++)
    #pragma unroll
    for (int r = 0; r < 4; r++) {
      float s1 = acc[mi][0][r] * a1v[0] + acc[mi][1][r] * a1v[1];
      float s2 = acc[mi][0][r] * a2v[0] + acc[mi][1][r] * a2v[1];
      #pragma unroll
      for (int off = 1; off < 16; off <<= 1) {
        s1 += __shfl_xor(s1, off);
        s2 += __shfl_xor(s2, off);
      }
      if (lr == 0) {
        int row = i0 + wr * 64 + mi * 16 + lslot * 4 + r;
        atomicAdd(&s1T[row * NH + h], s1);
        atomicAdd(&s2H[(size_t)h * NN + row], s2);
      }
    }

  // ---- transposed f16 write via padded LDS tile [64][132] (reuses As) ----
  u16* tp = (u16*)As;
  #pragma unroll
  for (int mi = 0; mi < 4; mi++)
    #pragma unroll
    for (int ni = 0; ni < 2; ni++)
      #pragma unroll
      for (int rp = 0; rp < 2; rp++) {
        unsigned pw = (unsigned)f2h_bits(acc[mi][ni][2 * rp]) |
                      ((unsigned)f2h_bits(acc[mi][ni][2 * rp + 1]) << 16);
        int d = wc * 32 + ni * 16 + lr;
        int i = wr * 64 + mi * 16 + lslot * 4 + 2 * rp;
        *reinterpret_cast<unsigned*>(&tp[d * 132 + i]) = pw;
      }
  __syncthreads();
  const int dd = tid >> 2, ic = (tid & 3) * 32;
  u16* go = seqTh + (size_t)(h * DH + dd) * NN + i0 + ic;
  #pragma unroll
  for (int q = 0; q < 8; q++) {
    u16x4 v = *reinterpret_cast<const u16x4*>(&tp[dd * 132 + ic + q * 4]);
    *reinterpret_cast<u16x4*>(go + q * 4) = v;
  }
}

// ---------------- bf16 GEMM (m97-style + counted vmcnt): ELU epilogue ----------------
__global__ __launch_bounds__(256, 2) void gemm_bt(const u16* __restrict__ A,
                                                  const u16* __restrict__ BT,
                                                  float* __restrict__ Cf,
                                                  const float* __restrict__ bias,
                                                  int M, int N, int K) {
  __shared__ __align__(16) u16 As[2][128 * 64];
  __shared__ __align__(16) u16 Bs[2][64 * 64];
  const int tid = threadIdx.x;
  const int i0 = blockIdx.x * 128, n0 = blockIdx.y * 64;
  const int w = tid >> 6, l = tid & 63;
  const int wr = w >> 1, wc = w & 1;
  const int lr = l & 15, lslot = l >> 4;
  const int wu = __builtin_amdgcn_readfirstlane(w);
  const int srow_lo = l >> 3, sg = (l & 7) ^ (srow_lo & 7);
  const u16* gA[4];
  #pragma unroll
  for (int jj = 0; jj < 4; jj++)
    gA[jj] = A + (size_t)(i0 + wu * 32 + jj * 8 + srow_lo) * K + sg * 8;
  const u16* gB[2];
  #pragma unroll
  for (int jb = 0; jb < 2; jb++)
    gB[jb] = BT + (size_t)(n0 + wu * 16 + jb * 8 + srow_lo) * K + sg * 8;

  fx4 acc[4][2] = {};

  #pragma unroll
  for (int jj = 0; jj < 4; jj++)
    gload16(gA[jj], (char*)As[0] + wu * 4096 + jj * 1024);
  #pragma unroll
  for (int jb = 0; jb < 2; jb++)
    gload16(gB[jb], (char*)Bs[0] + wu * 2048 + jb * 1024);
  __syncthreads();

  for (int kt = 0; kt < 16; kt++) {
    const int buf = kt & 1;
    __builtin_amdgcn_s_barrier();
    {
      const int kn = ((kt + 1) & 15) * 64;
      __builtin_amdgcn_sched_barrier(0);
      #pragma unroll
      for (int jj = 0; jj < 4; jj++)
        gload16(gA[jj] + kn, (char*)As[buf ^ 1] + wu * 4096 + jj * 1024);
      #pragma unroll
      for (int jb = 0; jb < 2; jb++)
        gload16(gB[jb] + kn, (char*)Bs[buf ^ 1] + wu * 2048 + jb * 1024);
      __builtin_amdgcn_sched_barrier(0);
      wait_vm6();
      __builtin_amdgcn_sched_barrier(0);
    }
    __builtin_amdgcn_s_barrier();
    #pragma unroll
    for (int ks = 0; ks < 2; ks++) {
      bf16x8 af[4], bfr[2];
      #pragma unroll
      for (int mi = 0; mi < 4; mi++) {
        const int r = wr * 64 + mi * 16 + lr;
        const int sl = (ks * 4 + lslot) ^ (r & 7);
        af[mi] = *reinterpret_cast<const bf16x8*>((const char*)As[buf] + r * 128 + sl * 16);
      }
      #pragma unroll
      for (int ni = 0; ni < 2; ni++) {
        const int r = wc * 32 + ni * 16 + lr;
        const int sl = (ks * 4 + lslot) ^ (r & 7);
        bfr[ni] = *reinterpret_cast<const bf16x8*>((const char*)Bs[buf] + r * 128 + sl * 16);
      }
      #pragma unroll
      for (int mi = 0; mi < 4; mi++)
        #pragma unroll
        for (int ni = 0; ni < 2; ni++)
          acc[mi][ni] = __builtin_amdgcn_mfma_f32_16x16x32_bf16(af[mi], bfr[ni], acc[mi][ni], 0, 0, 0);
    }
  }

  const int orow = wr * 64 + lslot * 4;
  const int ocol = wc * 32 + lr;
  #pragma unroll
  for (int mi = 0; mi < 4; mi++)
    #pragma unroll
    for (int r = 0; r < 4; r++)
      #pragma unroll
      for (int ni = 0; ni < 2; ni++) {
        int col = n0 + ocol + ni * 16;
        float v = acc[mi][ni][r] + bias[col];
        Cf[(size_t)(i0 + orow + mi * 16 + r) * N + col] = v > 0.f ? v : expm1f(v);
      }
}

// ---------------- per-head global max + packed f16 exp tables ----------------
__global__ __launch_bounds__(256) void prep_kernel(const float* __restrict__ s2H,
                                                   float* __restrict__ Dmax,
                                                   unsigned* __restrict__ epH2,
                                                   unsigned* __restrict__ enH2) {
  __shared__ float red[4];
  __shared__ float sDm;
  const int h = blockIdx.x, t = threadIdx.x;
  const fx4* d = reinterpret_cast<const fx4*>(s2H + (size_t)h * NN);
  fx4 v[4];
  float mx = -3e38f;
  #pragma unroll
  for (int q = 0; q < 4; q++) {
    v[q] = d[t * 4 + q];
    #pragma unroll
    for (int z = 0; z < 4; z++) mx = fmaxf(mx, v[q][z]);
  }
  #pragma unroll
  for (int off = 1; off < 64; off <<= 1) mx = fmaxf(mx, __shfl_xor(mx, off));
  if ((t & 63) == 0) red[t >> 6] = mx;
  __syncthreads();
  if (t == 0) {
    float m = fmaxf(fmaxf(red[0], red[1]), fmaxf(red[2], red[3]));
    sDm = m;
    Dmax[h] = m;
  }
  __syncthreads();
  const float Dm = sDm;
  #pragma unroll
  for (int q = 0; q < 8; q++) {
    float d0 = v[q >> 1][(q & 1) * 2];
    float d1 = v[q >> 1][(q & 1) * 2 + 1];
    unsigned ep = (unsigned)f2h_bits(__expf(d0 - Dm)) |
                  ((unsigned)f2h_bits(__expf(d1 - Dm)) << 16);
    unsigned en = (unsigned)f2h_bits(__expf(0.2f * (d0 - Dm))) |
                  ((unsigned)f2h_bits(__expf(0.2f * (d1 - Dm))) << 16);
    epH2[h * 2048 + t * 8 + q] = ep;
    enH2[h * 2048 + t * 8 + q] = en;
  }
}

// ---------------- adjacency -> byte mask (0xFF / 0x00 per col) ----------------
__global__ __launch_bounds__(256) void maskb_kernel(const float* __restrict__ adj,
                                                    unsigned char* __restrict__ mb) {
  size_t g = (size_t)blockIdx.x * 256 + threadIdx.x;
  const fx4* ap = reinterpret_cast<const fx4*>(adj) + g * 4;
  ux4 o;
  #pragma unroll
  for (int q = 0; q < 4; q++) {
    fx4 a = ap[q];
    unsigned b0 = a[0] > 0.5f ? 0xFFu : 0u;
    unsigned b1 = a[1] > 0.5f ? 0xFFu : 0u;
    unsigned b2 = a[2] > 0.5f ? 0xFFu : 0u;
    unsigned b3 = a[3] > 0.5f ? 0xFFu : 0u;
    o[q] = b0 | (b1 << 8) | (b2 << 16) | (b3 << 24);
  }
  reinterpret_cast<ux4*>(mb)[g] = o;
}

// ---------------- fused packed-f16 P-build + PV ----------------
__device__ __forceinline__ h16x8 build_p(unsigned Ai2, unsigned Bi2,
                                         ux4 ep, ux4 en, ux2 mk) {
  unsigned w0 = __builtin_amdgcn_perm(0u, mk[0], 0x01010000u);
  unsigned w1 = __builtin_amdgcn_perm(0u, mk[0], 0x03030202u);
  unsigned w2 = __builtin_amdgcn_perm(0u, mk[1], 0x01010000u);
  unsigned w3 = __builtin_amdgcn_perm(0u, mk[1], 0x03030202u);
  ux4 afw;
  afw[0] = pk_max(pk_mul(Ai2, ep[0]), pk_mul(Bi2, en[0])) & w0;
  afw[1] = pk_max(pk_mul(Ai2, ep[1]), pk_mul(Bi2, en[1])) & w1;
  afw[2] = pk_max(pk_mul(Ai2, ep[2]), pk_mul(Bi2, en[2])) & w2;
  afw[3] = pk_max(pk_mul(Ai2, ep[3]), pk_mul(Bi2, en[3])) & w3;
  return __builtin_bit_cast(h16x8, afw);
}

// block = 128 rows x 1 head, 512 threads (8 waves x 16 rows). grid = 512 head-major.
// DEPTH-2 pipeline: Vs[3] buffers; per iter issue [masks(JT+1), gloads(JT+2)],
// wait vmcnt(8) (completes masks(JT)+gload(JT); gload(JT+1) stays in flight)
// -> V-tiles get TWO compute phases of latency cover.
__global__ __launch_bounds__(512, 4) void pv_kernel(const unsigned char* __restrict__ maskB,
                                                    const u16* __restrict__ seqTh,
                                                    const float* __restrict__ s1T,
                                                    const float* __restrict__ Dmax,
                                                    const unsigned* __restrict__ epH2,
                                                    const unsigned* __restrict__ enH2,
                                                    u16* __restrict__ hiddenb) {
  __shared__ __align__(16) u16 Vs[3][64 * 128];   // 3 x 16 KB
  __shared__ __align__(16) unsigned epL[2048];    // 8 KB
  __shared__ __align__(16) unsigned enL[2048];    // 8 KB
  const int h = blockIdx.x >> 5, it = blockIdx.x & 31, i0 = it * 128;
  const int t = threadIdx.x, w = t >> 6, l = t & 63;
  const int lr = l & 15, hi = l >> 4, lk = hi * 8;
  const float Dm = Dmax[h];
  const int arow = i0 + w * 16 + lr;
  const float c = s1T[arow * NH + h];
  float mi = c + Dm;
  mi = mi > 0.f ? mi : 0.2f * mi;
  const unsigned Ai2 = pack2h(__expf(c + Dm - mi));
  const unsigned Bi2 = pack2h(__expf(0.2f * (c + Dm) - mi));
  // ---- stage exp tables to LDS (once): 512 threads x 1 ux4 each ----
  {
    const ux4* gep = reinterpret_cast<const ux4*>(epH2 + h * 2048);
    const ux4* gen = reinterpret_cast<const ux4*>(enH2 + h * 2048);
    ux4 e0 = gep[t];
    ux4 n0 = gen[t];
    *reinterpret_cast<ux4*>(&epL[t * 4]) = e0;
    *reinterpret_cast<ux4*>(&enL[t * 4]) = n0;
  }
  // ---- global_load_lds: wave w covers LDS bytes [w*2048, +2KB) = 2 instrs x 1KB ----
  const int wu = __builtin_amdgcn_readfirstlane(w);
  const u16* gsrc[2];
  #pragma unroll
  for (int i = 0; i < 2; i++) {
    int row = wu * 8 + i * 4 + (l >> 4);
    int g = (l & 15) ^ (row & 7);
    gsrc[i] = seqTh + (size_t)(h * DH + row) * NN + g * 8;
  }
  const unsigned char* gm0 = maskB + (size_t)arow * NN + lk;
  fx4 acc[4] = {};
  fx4 acc1 = {};
  h16x8 ones;
  #pragma unroll
  for (int e = 0; e < 8; e++) ones[e] = (_Float16)1.0f;

  ux2 mkS[2][2][2];   // [set][jj][ks]; set = JT&1

  // ---- prologue: masks(0) -> mkS[0]; gload(0) -> Vs[0]; gload(1) -> Vs[1] ----
  #pragma unroll
  for (int jj = 0; jj < 2; jj++)
    #pragma unroll
    for (int ks = 0; ks < 2; ks++)
      mkS[0][jj][ks] = *reinterpret_cast<const ux2*>(gm0 + jj * 64 + ks * 32);
  #pragma unroll
  for (int i = 0; i < 2; i++)
    gload16(gsrc[i], (char*)Vs[0] + wu * 2048 + i * 1024);
  #pragma unroll
  for (int i = 0; i < 2; i++)
    gload16(gsrc[i] + 128, (char*)Vs[1] + wu * 2048 + i * 1024);
  __syncthreads();   // tables visible (drains prologue batch; one-time)

  for (int JT = 0; JT < 32; JT++) {
    __builtin_amdgcn_s_barrier();             // compute(JT-1) done block-wide
    {
      const int jm = ((JT + 1) & 31) * 128;   // masks for JT+1 -> set (JT+1)&1
      const int jg = ((JT + 2) & 31) * 128;   // V-tile for JT+2 -> Vs[(JT+2)%3]
      u16* vdst = (u16*)Vs[(JT + 2) % 3];
      __builtin_amdgcn_sched_barrier(0);
      #pragma unroll
      for (int jj = 0; jj < 2; jj++)
        #pragma unroll
        for (int ks = 0; ks < 2; ks++)
          mkS[(JT + 1) & 1][jj][ks] =
              *reinterpret_cast<const ux2*>(gm0 + jm + jj * 64 + ks * 32);
      #pragma unroll
      for (int i = 0; i < 2; i++)
        gload16(gsrc[i] + jg, (char*)vdst + wu * 2048 + i * 1024);
      __builtin_amdgcn_sched_barrier(0);
      wait_vm8();                             // masks(JT) + gload(JT) landed
      __builtin_amdgcn_sched_barrier(0);
    }
    __builtin_amdgcn_s_barrier();             // landed block-wide
    const u16* vbuf = Vs[JT % 3];
    #pragma unroll
    for (int jj = 0; jj < 2; jj++) {
      #pragma unroll
      for (int ks = 0; ks < 2; ks++) {
        const int jp = JT * 64 + jj * 32 + ks * 16 + hi * 4;
        ux4 ep = *reinterpret_cast<const ux4*>(&epL[jp]);
        ux4 en = *reinterpret_cast<const ux4*>(&enL[jp]);
        h16x8 bfr[4];
        #pragma unroll
        for (int ni = 0; ni < 4; ni++) {
          const int row = ni * 16 + lr;
          const int colb = (jj * 128 + ks * 64 + hi * 16) ^ ((lr & 7) << 4);
          bfr[ni] = *reinterpret_cast<const h16x8*>((const char*)vbuf + row * 256 + colb);
        }
        h16x8 A = build_p(Ai2, Bi2, ep, en, mkS[JT & 1][jj][ks]);
        #pragma unroll
        for (int ni = 0; ni < 4; ni++)
          acc[ni] = __builtin_amdgcn_mfma_f32_16x16x32_f16(A, bfr[ni], acc[ni], 0, 0, 0);
        acc1 = __builtin_amdgcn_mfma_f32_16x16x32_f16(A, ones, acc1, 0, 0, 0);
      }
    }
  }

  #pragma unroll
  for (int r = 0; r < 4; r++) {
    int row = i0 + w * 16 + hi * 4 + r;
    float inv = 1.0f / acc1[r];
    #pragma unroll
    for (int ni = 0; ni < 4; ni++)
      hiddenb[(size_t)row * DIN + h * DH + ni * 16 + lr] = f2b(acc[ni][r] * inv);
  }
}

extern "C" void kernel_launch(void* const* d_in, const int* in_sizes, int n_in,
                              void* d_out, int out_size, void* d_ws, size_t ws_size,
                              hipStream_t stream) {
  const float* x = (const float*)d_in[0];
  const float* adj = (const float*)d_in[1];
  const float* W_seq = (const float*)d_in[2];
  const float* a1 = (const float*)d_in[3];
  const float* a2 = (const float*)d_in[4];
  const float* W_out = (const float*)d_in[5];
  const float* b_out = (const float*)d_in[6];

  char* ws = (char*)d_ws;
  u16* wsT   = (u16*)(ws);                         // 2 MB
  u16* woT   = (u16*)(ws + (2u << 20));            // 2 MB
  u16* seqTh = (u16*)(ws + (12u << 20));           // 8 MB (f16 bits, [d][n])
  u16* hid   = (u16*)(ws + (20u << 20));           // 8 MB (bf16)
  float* s1T = (float*)(ws + (28u << 20));         // 256 KB
  float* s2H = s1T + NN * NH;                      // 256 KB (contiguous after s1T)
  unsigned* epH2 = (unsigned*)(s2H + NN * NH);     // 128 KB
  unsigned* enH2 = epH2 + NH * 2048;               // 128 KB
  float* DmaxB = (float*)(enH2 + NH * 2048);       // 64 B
  u16* xb = (u16*)(ws + (29u << 20));              // 8 MB
  unsigned char* maskB = (unsigned char*)(ws + (29u << 20));  // 16 MB -> ends 45 MB

  cast_kernel<<<4096, 256, 0, stream>>>(x, xb, NN * DIN / 4);
  tcast_kernel<<<dim3(32, 32), 256, 0, stream>>>(W_seq, wsT, DIN, DIN);
  tcast_kernel<<<dim3(32, 32), 256, 0, stream>>>(W_out, woT, DIN, DIN);
  hipMemsetAsync(s1T, 0, 2u * NN * NH * sizeof(float), stream);
  gemm_seq<<<dim3(32, 16), 256, 0, stream>>>(xb, wsT, a1, a2, seqTh, s1T, s2H, DIN);
  prep_kernel<<<16, 256, 0, stream>>>(s2H, DmaxB, epH2, enH2);
  maskb_kernel<<<4096, 256, 0, stream>>>(adj, maskB);
  pv_kernel<<<512, 512, 0, stream>>>(maskB, seqTh, s1T, DmaxB, epH2, enH2, hid);
  gemm_bt<<<dim3(32, 16), 256, 0, stream>>>(hid, woT, (float*)d_out, b_out, NN, DIN, DIN);
}

// Round 18
// 148.271 us; speedup vs baseline: 1.1144x; 1.1144x over previous
//
#include <hip/hip_runtime.h>
#include <hip/hip_bf16.h>
#include <math.h>

#define NN 4096
#define DIN 1024
#define NH 16
#define DH 64

typedef unsigned short u16;
typedef unsigned long long u64;
typedef u16 u16x4 __attribute__((ext_vector_type(4)));
typedef u16 u16x8 __attribute__((ext_vector_type(8)));
typedef unsigned ux2 __attribute__((ext_vector_type(2)));
typedef unsigned ux4 __attribute__((ext_vector_type(4)));
typedef float fx4 __attribute__((ext_vector_type(4)));
typedef __bf16 bf16x8 __attribute__((ext_vector_type(8)));
typedef _Float16 h16x8 __attribute__((ext_vector_type(8)));

__device__ __forceinline__ u16 f2b(float f) {
  unsigned u = __float_as_uint(f);
  u += 0x7fff + ((u >> 16) & 1);
  return (u16)(u >> 16);
}
__device__ __forceinline__ float b2f(u16 h) {
  return __uint_as_float(((unsigned)h) << 16);
}
__device__ __forceinline__ u16 f2h_bits(float f) {
  _Float16 h = (_Float16)f;
  return __builtin_bit_cast(unsigned short, h);
}
__device__ __forceinline__ unsigned pack2h(float f) {
  unsigned hb = (unsigned)f2h_bits(f);
  return hb | (hb << 16);
}
__device__ __forceinline__ unsigned pk_mul(unsigned a, unsigned b) {
  unsigned d;
  asm("v_pk_mul_f16 %0, %1, %2" : "=v"(d) : "v"(a), "v"(b));
  return d;
}
__device__ __forceinline__ unsigned pk_max(unsigned a, unsigned b) {
  unsigned d;
  asm("v_pk_max_f16 %0, %1, %2" : "=v"(d) : "v"(a), "v"(b));
  return d;
}
// async global->LDS, 16B per lane; lds base wave-uniform, lane*16 auto-offset
__device__ __forceinline__ void gload16(const void* g, void* l) {
  __builtin_amdgcn_global_load_lds(
      (const __attribute__((address_space(1))) unsigned*)g,
      (__attribute__((address_space(3))) unsigned*)l, 16, 0, 0);
}
// counted wait: previous iteration's 6 VMEM ops complete; this iteration's 6 stay in flight
__device__ __forceinline__ void wait_vm6() {
  asm volatile("s_waitcnt vmcnt(6)" ::: "memory");
}

// ---------------- cast f32 -> bf16 (flat) ----------------
__global__ __launch_bounds__(256) void cast_kernel(const float* __restrict__ in,
                                                   u16* __restrict__ out, int n4) {
  int i = blockIdx.x * 256 + threadIdx.x;
  if (i < n4) {
    fx4 v = reinterpret_cast<const fx4*>(in)[i];
    u16x4 o;
    o[0] = f2b(v[0]); o[1] = f2b(v[1]); o[2] = f2b(v[2]); o[3] = f2b(v[3]);
    reinterpret_cast<u16x4*>(out)[i] = o;
  }
}

// ---------------- transpose+cast f32[R][C] -> bf16[C][R] ----------------
__global__ __launch_bounds__(256) void tcast_kernel(const float* __restrict__ in,
                                                    u16* __restrict__ out, int R, int C) {
  __shared__ u16 tile[32][33];
  int bc = blockIdx.x * 32, br = blockIdx.y * 32;
  int tx = threadIdx.x & 31, ty = threadIdx.x >> 5;
  #pragma unroll
  for (int r = ty; r < 32; r += 8)
    tile[r][tx] = f2b(in[(size_t)(br + r) * C + bc + tx]);
  __syncthreads();
  #pragma unroll
  for (int r = ty; r < 32; r += 8)
    out[(size_t)(bc + r) * R + br + tx] = tile[tx][r];
}

// ---- gemm1 fused: seq = xb@W_seq^T; writes seqTh (f16, [d][n]) + score partials ----
__global__ __launch_bounds__(256, 2) void gemm_seq(const u16* __restrict__ A,
                                                   const u16* __restrict__ BT,
                                                   const float* __restrict__ a1,
                                                   const float* __restrict__ a2,
                                                   u16* __restrict__ seqTh,
                                                   float* __restrict__ s1T,
                                                   float* __restrict__ s2H,
                                                   int K) {
  __shared__ __align__(16) u16 As[2][128 * 64];   // 2 x 16 KB
  __shared__ __align__(16) u16 Bs[2][64 * 64];    // 2 x 8 KB
  const int tid = threadIdx.x;
  const int i0 = blockIdx.x * 128, n0 = blockIdx.y * 64, h = blockIdx.y;
  const int w = tid >> 6, l = tid & 63;
  const int wr = w >> 1, wc = w & 1;
  const int lr = l & 15, lslot = l >> 4;
  const int wu = __builtin_amdgcn_readfirstlane(w);
  const int srow_lo = l >> 3, sg = (l & 7) ^ (srow_lo & 7);
  const u16* gA[4];
  #pragma unroll
  for (int jj = 0; jj < 4; jj++)
    gA[jj] = A + (size_t)(i0 + wu * 32 + jj * 8 + srow_lo) * K + sg * 8;
  const u16* gB[2];
  #pragma unroll
  for (int jb = 0; jb < 2; jb++)
    gB[jb] = BT + (size_t)(n0 + wu * 16 + jb * 8 + srow_lo) * K + sg * 8;

  fx4 acc[4][2] = {};

  #pragma unroll
  for (int jj = 0; jj < 4; jj++)
    gload16(gA[jj], (char*)As[0] + wu * 4096 + jj * 1024);
  #pragma unroll
  for (int jb = 0; jb < 2; jb++)
    gload16(gB[jb], (char*)Bs[0] + wu * 2048 + jb * 1024);
  __syncthreads();

  for (int kt = 0; kt < 16; kt++) {
    const int buf = kt & 1;
    __builtin_amdgcn_s_barrier();             // readers of buf^1 done
    {
      const int kn = ((kt + 1) & 15) * 64;    // wrapped -> count always exact
      __builtin_amdgcn_sched_barrier(0);
      #pragma unroll
      for (int jj = 0; jj < 4; jj++)
        gload16(gA[jj] + kn, (char*)As[buf ^ 1] + wu * 4096 + jj * 1024);
      #pragma unroll
      for (int jb = 0; jb < 2; jb++)
        gload16(gB[jb] + kn, (char*)Bs[buf ^ 1] + wu * 2048 + jb * 1024);
      __builtin_amdgcn_sched_barrier(0);
      wait_vm6();                             // tile kt landed (issued last iter)
      __builtin_amdgcn_sched_barrier(0);
    }
    __builtin_amdgcn_s_barrier();             // landed block-wide
    #pragma unroll
    for (int ks = 0; ks < 2; ks++) {
      bf16x8 af[4], bfr[2];
      #pragma unroll
      for (int mi = 0; mi < 4; mi++) {
        const int r = wr * 64 + mi * 16 + lr;
        const int sl = (ks * 4 + lslot) ^ (r & 7);
        af[mi] = *reinterpret_cast<const bf16x8*>((const char*)As[buf] + r * 128 + sl * 16);
      }
      #pragma unroll
      for (int ni = 0; ni < 2; ni++) {
        const int r = wc * 32 + ni * 16 + lr;
        const int sl = (ks * 4 + lslot) ^ (r & 7);
        bfr[ni] = *reinterpret_cast<const bf16x8*>((const char*)Bs[buf] + r * 128 + sl * 16);
      }
      #pragma unroll
      for (int mi = 0; mi < 4; mi++)
        #pragma unroll
        for (int ni = 0; ni < 2; ni++)
          acc[mi][ni] = __builtin_amdgcn_mfma_f32_16x16x32_bf16(af[mi], bfr[ni], acc[mi][ni], 0, 0, 0);
    }
  }
  __syncthreads();   // all compute done before As is reused as transpose scratch

  // ---- score partials: s1/s2 per row for this head ----
  float a1v[2], a2v[2];
  #pragma unroll
  for (int ni = 0; ni < 2; ni++) {
    int dl = wc * 32 + ni * 16 + lr;
    a1v[ni] = a1[dl];
    a2v[ni] = a2[dl];
  }
  #pragma unroll
  for (int mi = 0; mi < 4; mi++)
    #pragma unroll
    for (int r = 0; r < 4; r++) {
      float s1 = acc[mi][0][r] * a1v[0] + acc[mi][1][r] * a1v[1];
      float s2 = acc[mi][0][r] * a2v[0] + acc[mi][1][r] * a2v[1];
      #pragma unroll
      for (int off = 1; off < 16; off <<= 1) {
        s1 += __shfl_xor(s1, off);
        s2 += __shfl_xor(s2, off);
      }
      if (lr == 0) {
        int row = i0 + wr * 64 + mi * 16 + lslot * 4 + r;
        atomicAdd(&s1T[row * NH + h], s1);
        atomicAdd(&s2H[(size_t)h * NN + row], s2);
      }
    }

  // ---- transposed f16 write via padded LDS tile [64][132] (reuses As) ----
  u16* tp = (u16*)As;
  #pragma unroll
  for (int mi = 0; mi < 4; mi++)
    #pragma unroll
    for (int ni = 0; ni < 2; ni++)
      #pragma unroll
      for (int rp = 0; rp < 2; rp++) {
        unsigned pw = (unsigned)f2h_bits(acc[mi][ni][2 * rp]) |
                      ((unsigned)f2h_bits(acc[mi][ni][2 * rp + 1]) << 16);
        int d = wc * 32 + ni * 16 + lr;
        int i = wr * 64 + mi * 16 + lslot * 4 + 2 * rp;
        *reinterpret_cast<unsigned*>(&tp[d * 132 + i]) = pw;
      }
  __syncthreads();
  const int dd = tid >> 2, ic = (tid & 3) * 32;
  u16* go = seqTh + (size_t)(h * DH + dd) * NN + i0 + ic;
  #pragma unroll
  for (int q = 0; q < 8; q++) {
    u16x4 v = *reinterpret_cast<const u16x4*>(&tp[dd * 132 + ic + q * 4]);
    *reinterpret_cast<u16x4*>(go + q * 4) = v;
  }
}

// ---------------- bf16 GEMM (m97-style + counted vmcnt): ELU epilogue ----------------
__global__ __launch_bounds__(256, 2) void gemm_bt(const u16* __restrict__ A,
                                                  const u16* __restrict__ BT,
                                                  float* __restrict__ Cf,
                                                  const float* __restrict__ bias,
                                                  int M, int N, int K) {
  __shared__ __align__(16) u16 As[2][128 * 64];
  __shared__ __align__(16) u16 Bs[2][64 * 64];
  const int tid = threadIdx.x;
  const int i0 = blockIdx.x * 128, n0 = blockIdx.y * 64;
  const int w = tid >> 6, l = tid & 63;
  const int wr = w >> 1, wc = w & 1;
  const int lr = l & 15, lslot = l >> 4;
  const int wu = __builtin_amdgcn_readfirstlane(w);
  const int srow_lo = l >> 3, sg = (l & 7) ^ (srow_lo & 7);
  const u16* gA[4];
  #pragma unroll
  for (int jj = 0; jj < 4; jj++)
    gA[jj] = A + (size_t)(i0 + wu * 32 + jj * 8 + srow_lo) * K + sg * 8;
  const u16* gB[2];
  #pragma unroll
  for (int jb = 0; jb < 2; jb++)
    gB[jb] = BT + (size_t)(n0 + wu * 16 + jb * 8 + srow_lo) * K + sg * 8;

  fx4 acc[4][2] = {};

  #pragma unroll
  for (int jj = 0; jj < 4; jj++)
    gload16(gA[jj], (char*)As[0] + wu * 4096 + jj * 1024);
  #pragma unroll
  for (int jb = 0; jb < 2; jb++)
    gload16(gB[jb], (char*)Bs[0] + wu * 2048 + jb * 1024);
  __syncthreads();

  for (int kt = 0; kt < 16; kt++) {
    const int buf = kt & 1;
    __builtin_amdgcn_s_barrier();
    {
      const int kn = ((kt + 1) & 15) * 64;
      __builtin_amdgcn_sched_barrier(0);
      #pragma unroll
      for (int jj = 0; jj < 4; jj++)
        gload16(gA[jj] + kn, (char*)As[buf ^ 1] + wu * 4096 + jj * 1024);
      #pragma unroll
      for (int jb = 0; jb < 2; jb++)
        gload16(gB[jb] + kn, (char*)Bs[buf ^ 1] + wu * 2048 + jb * 1024);
      __builtin_amdgcn_sched_barrier(0);
      wait_vm6();
      __builtin_amdgcn_sched_barrier(0);
    }
    __builtin_amdgcn_s_barrier();
    #pragma unroll
    for (int ks = 0; ks < 2; ks++) {
      bf16x8 af[4], bfr[2];
      #pragma unroll
      for (int mi = 0; mi < 4; mi++) {
        const int r = wr * 64 + mi * 16 + lr;
        const int sl = (ks * 4 + lslot) ^ (r & 7);
        af[mi] = *reinterpret_cast<const bf16x8*>((const char*)As[buf] + r * 128 + sl * 16);
      }
      #pragma unroll
      for (int ni = 0; ni < 2; ni++) {
        const int r = wc * 32 + ni * 16 + lr;
        const int sl = (ks * 4 + lslot) ^ (r & 7);
        bfr[ni] = *reinterpret_cast<const bf16x8*>((const char*)Bs[buf] + r * 128 + sl * 16);
      }
      #pragma unroll
      for (int mi = 0; mi < 4; mi++)
        #pragma unroll
        for (int ni = 0; ni < 2; ni++)
          acc[mi][ni] = __builtin_amdgcn_mfma_f32_16x16x32_bf16(af[mi], bfr[ni], acc[mi][ni], 0, 0, 0);
    }
  }

  const int orow = wr * 64 + lslot * 4;
  const int ocol = wc * 32 + lr;
  #pragma unroll
  for (int mi = 0; mi < 4; mi++)
    #pragma unroll
    for (int r = 0; r < 4; r++)
      #pragma unroll
      for (int ni = 0; ni < 2; ni++) {
        int col = n0 + ocol + ni * 16;
        float v = acc[mi][ni][r] + bias[col];
        Cf[(size_t)(i0 + orow + mi * 16 + r) * N + col] = v > 0.f ? v : expm1f(v);
      }
}

// ---------------- per-head global max + packed f16 exp tables ----------------
__global__ __launch_bounds__(256) void prep_kernel(const float* __restrict__ s2H,
                                                   float* __restrict__ Dmax,
                                                   unsigned* __restrict__ epH2,
                                                   unsigned* __restrict__ enH2) {
  __shared__ float red[4];
  __shared__ float sDm;
  const int h = blockIdx.x, t = threadIdx.x;
  const fx4* d = reinterpret_cast<const fx4*>(s2H + (size_t)h * NN);
  fx4 v[4];
  float mx = -3e38f;
  #pragma unroll
  for (int q = 0; q < 4; q++) {
    v[q] = d[t * 4 + q];
    #pragma unroll
    for (int z = 0; z < 4; z++) mx = fmaxf(mx, v[q][z]);
  }
  #pragma unroll
  for (int off = 1; off < 64; off <<= 1) mx = fmaxf(mx, __shfl_xor(mx, off));
  if ((t & 63) == 0) red[t >> 6] = mx;
  __syncthreads();
  if (t == 0) {
    float m = fmaxf(fmaxf(red[0], red[1]), fmaxf(red[2], red[3]));
    sDm = m;
    Dmax[h] = m;
  }
  __syncthreads();
  const float Dm = sDm;
  #pragma unroll
  for (int q = 0; q < 8; q++) {
    float d0 = v[q >> 1][(q & 1) * 2];
    float d1 = v[q >> 1][(q & 1) * 2 + 1];
    unsigned ep = (unsigned)f2h_bits(__expf(d0 - Dm)) |
                  ((unsigned)f2h_bits(__expf(d1 - Dm)) << 16);
    unsigned en = (unsigned)f2h_bits(__expf(0.2f * (d0 - Dm))) |
                  ((unsigned)f2h_bits(__expf(0.2f * (d1 - Dm))) << 16);
    epH2[h * 2048 + t * 8 + q] = ep;
    enH2[h * 2048 + t * 8 + q] = en;
  }
}

// ---------------- adjacency -> byte mask (0xFF / 0x00 per col) ----------------
__global__ __launch_bounds__(256) void maskb_kernel(const float* __restrict__ adj,
                                                    unsigned char* __restrict__ mb) {
  size_t g = (size_t)blockIdx.x * 256 + threadIdx.x;
  const fx4* ap = reinterpret_cast<const fx4*>(adj) + g * 4;
  ux4 o;
  #pragma unroll
  for (int q = 0; q < 4; q++) {
    fx4 a = ap[q];
    unsigned b0 = a[0] > 0.5f ? 0xFFu : 0u;
    unsigned b1 = a[1] > 0.5f ? 0xFFu : 0u;
    unsigned b2 = a[2] > 0.5f ? 0xFFu : 0u;
    unsigned b3 = a[3] > 0.5f ? 0xFFu : 0u;
    o[q] = b0 | (b1 << 8) | (b2 << 16) | (b3 << 24);
  }
  reinterpret_cast<ux4*>(mb)[g] = o;
}

// ---------------- fused packed-f16 P-build + PV ----------------
__device__ __forceinline__ h16x8 build_p(unsigned Ai2, unsigned Bi2,
                                         ux4 ep, ux4 en, ux2 mk) {
  unsigned w0 = __builtin_amdgcn_perm(0u, mk[0], 0x01010000u);
  unsigned w1 = __builtin_amdgcn_perm(0u, mk[0], 0x03030202u);
  unsigned w2 = __builtin_amdgcn_perm(0u, mk[1], 0x01010000u);
  unsigned w3 = __builtin_amdgcn_perm(0u, mk[1], 0x03030202u);
  ux4 afw;
  afw[0] = pk_max(pk_mul(Ai2, ep[0]), pk_mul(Bi2, en[0])) & w0;
  afw[1] = pk_max(pk_mul(Ai2, ep[1]), pk_mul(Bi2, en[1])) & w1;
  afw[2] = pk_max(pk_mul(Ai2, ep[2]), pk_mul(Bi2, en[2])) & w2;
  afw[3] = pk_max(pk_mul(Ai2, ep[3]), pk_mul(Bi2, en[3])) & w3;
  return __builtin_bit_cast(h16x8, afw);
}

// block = 128 rows x 1 head, 512 threads (8 waves x 16 rows). grid = 512 head-major.
// counted vmcnt(6) + raw barriers replace the full drain (T4). [R13 proven optimum]
__global__ __launch_bounds__(512, 4) void pv_kernel(const unsigned char* __restrict__ maskB,
                                                    const u16* __restrict__ seqTh,
                                                    const float* __restrict__ s1T,
                                                    const float* __restrict__ Dmax,
                                                    const unsigned* __restrict__ epH2,
                                                    const unsigned* __restrict__ enH2,
                                                    u16* __restrict__ hiddenb) {
  __shared__ __align__(16) u16 Vs[2][64 * 128];   // 2 x 16 KB
  __shared__ __align__(16) unsigned epL[2048];    // 8 KB
  __shared__ __align__(16) unsigned enL[2048];    // 8 KB
  const int h = blockIdx.x >> 5, it = blockIdx.x & 31, i0 = it * 128;
  const int t = threadIdx.x, w = t >> 6, l = t & 63;
  const int lr = l & 15, hi = l >> 4, lk = hi * 8;
  const float Dm = Dmax[h];
  const int arow = i0 + w * 16 + lr;
  const float c = s1T[arow * NH + h];
  float mi = c + Dm;
  mi = mi > 0.f ? mi : 0.2f * mi;
  const unsigned Ai2 = pack2h(__expf(c + Dm - mi));
  const unsigned Bi2 = pack2h(__expf(0.2f * (c + Dm) - mi));
  {
    const ux4* gep = reinterpret_cast<const ux4*>(epH2 + h * 2048);
    const ux4* gen = reinterpret_cast<const ux4*>(enH2 + h * 2048);
    ux4 e0 = gep[t];
    ux4 n0 = gen[t];
    *reinterpret_cast<ux4*>(&epL[t * 4]) = e0;
    *reinterpret_cast<ux4*>(&enL[t * 4]) = n0;
  }
  const int wu = __builtin_amdgcn_readfirstlane(w);
  const u16* gsrc[2];
  #pragma unroll
  for (int i = 0; i < 2; i++) {
    int row = wu * 8 + i * 4 + (l >> 4);
    int g = (l & 15) ^ (row & 7);
    gsrc[i] = seqTh + (size_t)(h * DH + row) * NN + g * 8;
  }
  const unsigned char* gm0 = maskB + (size_t)arow * NN + lk;
  fx4 acc[4] = {};
  fx4 acc1 = {};
  h16x8 ones;
  #pragma unroll
  for (int e = 0; e < 8; e++) ones[e] = (_Float16)1.0f;

  #pragma unroll
  for (int i = 0; i < 2; i++)
    gload16(gsrc[i], (char*)Vs[0] + wu * 2048 + i * 1024);
  ux2 mkc[2][2], mkn[2][2];
  #pragma unroll
  for (int jj = 0; jj < 2; jj++)
    #pragma unroll
    for (int ks = 0; ks < 2; ks++)
      mkc[jj][ks] = *reinterpret_cast<const ux2*>(gm0 + jj * 64 + ks * 32);
  __syncthreads();

  for (int JT = 0; JT < 32; JT++) {
    const int buf = JT & 1;
    __builtin_amdgcn_s_barrier();             // readers of Vs[buf^1] done
    {
      const int jn = ((JT + 1) & 31) * 128;   // wrapped -> 6 ops every iter
      __builtin_amdgcn_sched_barrier(0);
      #pragma unroll
      for (int i = 0; i < 2; i++)
        gload16(gsrc[i] + jn, (char*)Vs[buf ^ 1] + wu * 2048 + i * 1024);
      #pragma unroll
      for (int jj = 0; jj < 2; jj++)
        #pragma unroll
        for (int ks = 0; ks < 2; ks++)
          mkn[jj][ks] = *reinterpret_cast<const ux2*>(gm0 + jn + jj * 64 + ks * 32);
      __builtin_amdgcn_sched_barrier(0);
      wait_vm6();                             // tile JT + masks JT landed
      __builtin_amdgcn_sched_barrier(0);
    }
    __builtin_amdgcn_s_barrier();             // landed block-wide
    #pragma unroll
    for (int jj = 0; jj < 2; jj++) {
      #pragma unroll
      for (int ks = 0; ks < 2; ks++) {
        const int jp = JT * 64 + jj * 32 + ks * 16 + hi * 4;
        ux4 ep = *reinterpret_cast<const ux4*>(&epL[jp]);
        ux4 en = *reinterpret_cast<const ux4*>(&enL[jp]);
        h16x8 bfr[4];
        #pragma unroll
        for (int ni = 0; ni < 4; ni++) {
          const int row = ni * 16 + lr;
          const int colb = (jj * 128 + ks * 64 + hi * 16) ^ ((lr & 7) << 4);
          bfr[ni] = *reinterpret_cast<const h16x8*>((const char*)Vs[buf] + row * 256 + colb);
        }
        h16x8 A = build_p(Ai2, Bi2, ep, en, mkc[jj][ks]);
        #pragma unroll
        for (int ni = 0; ni < 4; ni++)
          acc[ni] = __builtin_amdgcn_mfma_f32_16x16x32_f16(A, bfr[ni], acc[ni], 0, 0, 0);
        acc1 = __builtin_amdgcn_mfma_f32_16x16x32_f16(A, ones, acc1, 0, 0, 0);
      }
    }
    #pragma unroll
    for (int jj = 0; jj < 2; jj++)
      #pragma unroll
      for (int ks = 0; ks < 2; ks++)
        mkc[jj][ks] = mkn[jj][ks];
  }

  #pragma unroll
  for (int r = 0; r < 4; r++) {
    int row = i0 + w * 16 + hi * 4 + r;
    float inv = 1.0f / acc1[r];
    #pragma unroll
    for (int ni = 0; ni < 4; ni++)
      hiddenb[(size_t)row * DIN + h * DH + ni * 16 + lr] = f2b(acc[ni][r] * inv);
  }
}

extern "C" void kernel_launch(void* const* d_in, const int* in_sizes, int n_in,
                              void* d_out, int out_size, void* d_ws, size_t ws_size,
                              hipStream_t stream) {
  const float* x = (const float*)d_in[0];
  const float* adj = (const float*)d_in[1];
  const float* W_seq = (const float*)d_in[2];
  const float* a1 = (const float*)d_in[3];
  const float* a2 = (const float*)d_in[4];
  const float* W_out = (const float*)d_in[5];
  const float* b_out = (const float*)d_in[6];

  char* ws = (char*)d_ws;
  u16* wsT   = (u16*)(ws);                         // 2 MB
  u16* woT   = (u16*)(ws + (2u << 20));            // 2 MB
  u16* seqTh = (u16*)(ws + (12u << 20));           // 8 MB (f16 bits, [d][n])
  u16* hid   = (u16*)(ws + (20u << 20));           // 8 MB (bf16)
  float* s1T = (float*)(ws + (28u << 20));         // 256 KB
  float* s2H = s1T + NN * NH;                      // 256 KB (contiguous after s1T)
  unsigned* epH2 = (unsigned*)(s2H + NN * NH);     // 128 KB
  unsigned* enH2 = epH2 + NH * 2048;               // 128 KB
  float* DmaxB = (float*)(enH2 + NH * 2048);       // 64 B
  u16* xb = (u16*)(ws + (29u << 20));              // 8 MB
  unsigned char* maskB = (unsigned char*)(ws + (38u << 20));  // 16 MB (own region)

  cast_kernel<<<4096, 256, 0, stream>>>(x, xb, NN * DIN / 4);
  tcast_kernel<<<dim3(32, 32), 256, 0, stream>>>(W_seq, wsT, DIN, DIN);
  tcast_kernel<<<dim3(32, 32), 256, 0, stream>>>(W_out, woT, DIN, DIN);
  hipMemsetAsync(s1T, 0, 2u * NN * NH * sizeof(float), stream);
  gemm_seq<<<dim3(32, 16), 256, 0, stream>>>(xb, wsT, a1, a2, seqTh, s1T, s2H, DIN);
  prep_kernel<<<16, 256, 0, stream>>>(s2H, DmaxB, epH2, enH2);
  maskb_kernel<<<4096, 256, 0, stream>>>(adj, maskB);
  pv_kernel<<<512, 512, 0, stream>>>(maskB, seqTh, s1T, DmaxB, epH2, enH2, hid);
  gemm_bt<<<dim3(32, 16), 256, 0, stream>>>(hid, woT, (float*)d_out, b_out, NN, DIN, DIN);
}